// Round 1
// baseline (2726.393 us; speedup 1.0000x reference)
//
#include <hip/hip_runtime.h>
#include <hip/hip_bf16.h>
#include <stdint.h>

#define TT 128
#define BB 32
#define EE 512
#define HH 1024
#define VV 32000

typedef unsigned short u16;
typedef short bf16x8 __attribute__((ext_vector_type(8)));
typedef float f32x4 __attribute__((ext_vector_type(4)));

__device__ __forceinline__ u16 f2bf(float f) {
    unsigned int u = __builtin_bit_cast(unsigned int, f);
    u = (u + 0x7fffu + ((u >> 16) & 1u)) >> 16;
    return (u16)u;
}

__device__ __forceinline__ void gld_lds16(const u16* g, u16* l) {
    __builtin_amdgcn_global_load_lds(
        (__attribute__((address_space(1))) void*)g,
        (__attribute__((address_space(3))) void*)l, 16, 0, 0);
}

// ---------------- fp32 -> bf16 cast, 4 elems/thread ----------------
__global__ void k_cast(const float* __restrict__ s, u16* __restrict__ d, int n4) {
    int i = blockIdx.x * blockDim.x + threadIdx.x;
    if (i < n4) {
        float4 v = ((const float4*)s)[i];
        ushort4 o = { f2bf(v.x), f2bf(v.y), f2bf(v.z), f2bf(v.w) };
        ((ushort4*)d)[i] = o;
    }
}

// ---------------- embedding gather (with teacher-forcing shift) + cast ----------------
__global__ void k_embed(const int* __restrict__ inp, const float* __restrict__ emb,
                        u16* __restrict__ x) {
    int row = blockIdx.x;            // t*32 + b
    int t = row >> 5, b = row & 31;
    int st = (t == 0) ? 0 : (t - 1);
    int idx = inp[st * BB + b];
    int e = threadIdx.x * 4;         // 128 threads * 4 = 512
    float4 v = *(const float4*)(emb + (size_t)idx * EE + e);
    ushort4 o = { f2bf(v.x), f2bf(v.y), f2bf(v.z), f2bf(v.w) };
    *(ushort4*)(x + (size_t)row * EE + e) = o;
}

// ---------------- bf16 GEMM, C[M,N] = A[M,K] * B[N,K]^T + bias[N] ----------------
// m97 structure: 128x128 tile, BK=32, 256 threads = 4 waves (2x2 of 64x64),
// global_load_lds width 16 staging, 16x16x32 bf16 MFMA.
__global__ __launch_bounds__(256) void k_gemm_bt(
    const u16* __restrict__ A, const u16* __restrict__ B,
    const float* __restrict__ bias, float* __restrict__ C,
    int M, int N, int K)
{
    __shared__ u16 As[128 * 32];
    __shared__ u16 Bs[128 * 32];
    const int tid  = threadIdx.x;
    const int wave = tid >> 6;
    const int lane = tid & 63;
    const int m0 = blockIdx.y * 128;
    const int n0 = blockIdx.x * 128;
    const int wm = wave & 1;          // M half
    const int wn = wave >> 1;         // N half

    f32x4 acc[4][4];
    #pragma unroll
    for (int i = 0; i < 4; ++i)
        #pragma unroll
        for (int j = 0; j < 4; ++j) {
            f32x4 z = {0.f, 0.f, 0.f, 0.f};
            acc[i][j] = z;
        }

    const int srow = tid >> 2;         // staging row within 64-row half
    const int scol = (tid & 3) * 8;    // staging col (bf16 elems)
    const int mrow = wm * 64 + (lane & 15);
    const int nrow = wn * 64 + (lane & 15);
    const int kq   = (lane >> 4) * 8;

    for (int k0 = 0; k0 < K; k0 += 32) {
        __syncthreads();
        #pragma unroll
        for (int i = 0; i < 2; ++i) {
            int row = i * 64 + srow;
            gld_lds16(A + (size_t)(m0 + row) * K + k0 + scol,
                      As + (size_t)(i * 256 + wave * 64) * 8);
            gld_lds16(B + (size_t)(n0 + row) * K + k0 + scol,
                      Bs + (size_t)(i * 256 + wave * 64) * 8);
        }
        __syncthreads();

        bf16x8 a[4], b[4];
        #pragma unroll
        for (int x = 0; x < 4; ++x) {
            a[x] = *(const bf16x8*)&As[(mrow + x * 16) * 32 + kq];
            b[x] = *(const bf16x8*)&Bs[(nrow + x * 16) * 32 + kq];
        }
        #pragma unroll
        for (int mi = 0; mi < 4; ++mi)
            #pragma unroll
            for (int ni = 0; ni < 4; ++ni)
                acc[mi][ni] = __builtin_amdgcn_mfma_f32_16x16x32_bf16(
                    a[mi], b[ni], acc[mi][ni], 0, 0, 0);
    }

    // epilogue: C/D layout col = lane&15, row = (lane>>4)*4 + reg
    const int rbase = m0 + wm * 64 + (lane >> 4) * 4;
    const int cbase = n0 + wn * 64 + (lane & 15);
    #pragma unroll
    for (int mi = 0; mi < 4; ++mi) {
        #pragma unroll
        for (int ni = 0; ni < 4; ++ni) {
            int c = cbase + ni * 16;
            float bv = bias[c];
            int r0 = rbase + mi * 16;
            #pragma unroll
            for (int rr = 0; rr < 4; ++rr)
                C[(size_t)(r0 + rr) * N + c] = acc[mi][ni][rr] + bv;
        }
    }
}

// ---------------- one GRU step: gh = h@w_hh^T, gates, h_new ----------------
// grid: 64 blocks (16 cols each), 192 threads = 3 waves (one per gate r/z/n).
// Each wave computes the 32x16 gh tile for its gate (2 MFMA tiles, shared B frag).
__global__ __launch_bounds__(192) void k_gru_step(
    const float* __restrict__ gxt,      // [32, 3H] slice for this t
    const u16*   __restrict__ hprev_bf, // [32, H] bf16
    const float* __restrict__ hprev_f,  // [32, H] fp32
    const u16*   __restrict__ whh,      // [3H, H] bf16
    const float* __restrict__ bhh,      // [3H]
    float* __restrict__ hout_f,         // [32, H]
    u16*   __restrict__ hout_bf)        // [32, H]
{
    __shared__ float gh[3][2][16][16];
    const int tid  = threadIdx.x;
    const int wave = tid >> 6;          // gate: 0=r, 1=z, 2=n
    const int lane = tid & 63;
    const int j0   = blockIdx.x * 16;
    const int c16  = lane & 15;
    const int kq   = (lane >> 4) * 8;

    f32x4 acc0 = {0.f, 0.f, 0.f, 0.f};
    f32x4 acc1 = {0.f, 0.f, 0.f, 0.f};
    const u16* brow  = whh + (size_t)(wave * HH + j0 + c16) * HH;
    const u16* arow0 = hprev_bf + (size_t)c16 * HH;
    const u16* arow1 = hprev_bf + (size_t)(16 + c16) * HH;

    for (int kk = 0; kk < HH; kk += 32) {
        bf16x8 b  = *(const bf16x8*)&brow[kk + kq];
        bf16x8 a0 = *(const bf16x8*)&arow0[kk + kq];
        bf16x8 a1 = *(const bf16x8*)&arow1[kk + kq];
        acc0 = __builtin_amdgcn_mfma_f32_16x16x32_bf16(a0, b, acc0, 0, 0, 0);
        acc1 = __builtin_amdgcn_mfma_f32_16x16x32_bf16(a1, b, acc1, 0, 0, 0);
    }

    #pragma unroll
    for (int rr = 0; rr < 4; ++rr) {
        gh[wave][0][(lane >> 4) * 4 + rr][c16] = acc0[rr];
        gh[wave][1][(lane >> 4) * 4 + rr][c16] = acc1[rr];
    }
    __syncthreads();

    for (int e = tid; e < BB * 16; e += 192) {
        int row = e >> 4, col = e & 15;
        int j = j0 + col;
        int m = row >> 4, rl = row & 15;
        float hr = gh[0][m][rl][col] + bhh[j];
        float hz = gh[1][m][rl][col] + bhh[HH + j];
        float hn = gh[2][m][rl][col] + bhh[2 * HH + j];
        const float* gxrow = gxt + (size_t)row * (3 * HH);
        float r = 1.f / (1.f + expf(-(gxrow[j] + hr)));
        float z = 1.f / (1.f + expf(-(gxrow[HH + j] + hz)));
        float n = tanhf(gxrow[2 * HH + j] + r * hn);
        float hnew = (1.f - z) * n + z * hprev_f[(size_t)row * HH + j];
        hout_f[(size_t)row * HH + j] = hnew;
        hout_bf[(size_t)row * HH + j] = f2bf(hnew);
    }
}

extern "C" void kernel_launch(void* const* d_in, const int* in_sizes, int n_in,
                              void* d_out, int out_size, void* d_ws, size_t ws_size,
                              hipStream_t stream) {
    const int*   inputs = (const int*)d_in[0];
    // d_in[1] encoder_output, d_in[2] encoder_mask: unused by reference
    const float* emb    = (const float*)d_in[3];
    const float* w_ih   = (const float*)d_in[4];
    const float* w_hh   = (const float*)d_in[5];
    const float* b_ih   = (const float*)d_in[6];
    const float* b_hh   = (const float*)d_in[7];
    const float* out_w  = (const float*)d_in[8];
    const float* out_b  = (const float*)d_in[9];
    float* out = (float*)d_out;

    char* ws = (char*)d_ws;
    // workspace layout (bytes)
    u16*   wih_bf  = (u16*)  (ws + 0);          //  3,145,728
    u16*   whh_bf  = (u16*)  (ws + 3145728);    //  6,291,456
    u16*   outw_bf = (u16*)  (ws + 9437184);    // 65,536,000
    u16*   x_bf    = (u16*)  (ws + 74973184);   //  4,194,304
    float* gx      = (float*)(ws + 79167488);   // 50,331,648
    u16*   hseq    = (u16*)  (ws + 129499136);  //  8,388,608
    u16*   hz_bf   = (u16*)  (ws + 137887744);  //     65,536
    float* h0      = (float*)(ws + 137953280);  //    131,072
    float* h1      = (float*)(ws + 138084352);  //    131,072  (end 138,215,424)
    float* hbuf[2] = { h0, h1 };

    // 1) casts to bf16
    k_cast<<<1536,  256, 0, stream>>>(w_ih,  wih_bf,  (3*HH*EE)/4);
    k_cast<<<3072,  256, 0, stream>>>(w_hh,  whh_bf,  (3*HH*HH)/4);
    k_cast<<<32000, 256, 0, stream>>>(out_w, outw_bf, ((size_t)VV*HH)/4);
    // 2) embedding gather (shifted) + cast
    k_embed<<<TT*BB, 128, 0, stream>>>(inputs, emb, x_bf);
    // 3) gx = x @ w_ih^T + b_ih   [4096, 3072]
    {
        dim3 g(3*HH/128, (TT*BB)/128);
        k_gemm_bt<<<g, 256, 0, stream>>>(x_bf, wih_bf, b_ih, gx, TT*BB, 3*HH, EE);
    }
    // 4) init h = 0
    hipMemsetAsync(h0, 0, BB*HH*sizeof(float), stream);
    hipMemsetAsync(hz_bf, 0, BB*HH*sizeof(u16), stream);
    // 5) GRU scan
    for (int t = 0; t < TT; ++t) {
        const u16*   hb = (t == 0) ? hz_bf : hseq + (size_t)(t-1)*BB*HH;
        const float* hf = hbuf[t & 1];
        float*       ho = hbuf[(t + 1) & 1];
        k_gru_step<<<HH/16, 192, 0, stream>>>(gx + (size_t)t*BB*3*HH, hb, hf,
                                              whh_bf, b_hh, ho,
                                              hseq + (size_t)t*BB*HH);
    }
    // 6) logits = outputs @ out_w^T + out_b   [4096, 32000] -> d_out
    {
        dim3 g(VV/128, (TT*BB)/128);
        k_gemm_bt<<<g, 256, 0, stream>>>(hseq, outw_bf, out_b, out, TT*BB, VV, HH);
    }
    // 7) hidden state (fp32, after step 127 it lives in hbuf[0])
    hipMemcpyAsync(out + (size_t)TT*BB*VV, hbuf[0], BB*HH*sizeof(float),
                   hipMemcpyDeviceToDevice, stream);
}